// Round 1
// baseline (1464.732 us; speedup 1.0000x reference)
//
#include <hip/hip_runtime.h>
#include <math.h>

// Shapes fixed by the reference: N=65536 (derived), D=384, 2D=768, L=64, H=64, R=8, K=2
#define AUX_SLOTS 1024

__global__ void vl_kernel(const float* __restrict__ llm, const float* __restrict__ Vw,
                          const float* __restrict__ Vb, float* __restrict__ vl) {
    int b = blockIdx.x;          // b = r*64 + l
    int r = b >> 6, l = b & 63;
    int t = threadIdx.x;         // h
    float acc = Vb[r * 64 + t];
    const float* w = Vw + (size_t)(r * 384) * 64 + t;
    const float* xr = llm + l * 384;
#pragma unroll 4
    for (int d = 0; d < 384; ++d) acc += xr[d] * w[(size_t)d * 64];
    float ss = acc * acc;
#pragma unroll
    for (int m = 1; m < 64; m <<= 1) ss += __shfl_xor(ss, m);
    float inv = 1.0f / fmaxf(sqrtf(ss), 1e-12f);
    vl[(size_t)b * 64 + t] = acc * inv;
}

__global__ void __launch_bounds__(64) main_kernel(
    const float* __restrict__ eh, const float* __restrict__ sr,
    const float* __restrict__ rnd,
    const float* __restrict__ gw_, const float* __restrict__ gb_,
    const float* __restrict__ Uw, const float* __restrict__ Ub,
    const float* __restrict__ vl, float* __restrict__ aux,
    float* __restrict__ out, int N)
{
    int n = blockIdx.x, t = threadIdx.x;
    __shared__ float xs[768];
    __shared__ float us[64];
    __shared__ float ps[64];

    // ---- load x = concat(eh[n], sr[n]) as float4 ----
    {
        const float4* a = (const float4*)(eh + (size_t)n * 384);  // 96 float4
        const float4* b = (const float4*)(sr + (size_t)n * 384);  // 96 float4
        float4* xv = (float4*)xs;
#pragma unroll
        for (int i = 0; i < 3; ++i) {
            int idx = t + i * 64;
            xv[idx] = (idx < 96) ? a[idx] : b[idx - 96];
        }
    }
    __syncthreads();

    // ---- gate logits: lane t covers d in [12t, 12t+12) for all 8 routers ----
    float lg[8];
#pragma unroll
    for (int r = 0; r < 8; ++r) lg[r] = 0.f;
    {
        const float* g = gw_ + t * 12 * 8;
#pragma unroll
        for (int j = 0; j < 12; ++j) {
            float xd = xs[t * 12 + j];
#pragma unroll
            for (int r = 0; r < 8; ++r) lg[r] += xd * g[j * 8 + r];
        }
    }
#pragma unroll
    for (int m = 1; m < 64; m <<= 1) {
#pragma unroll
        for (int r = 0; r < 8; ++r) lg[r] += __shfl_xor(lg[r], m);
    }
#pragma unroll
    for (int r = 0; r < 8; ++r) lg[r] += gb_[r];

    // ---- softmax over routers (for aux), all lanes redundantly ----
    float mx = lg[0];
#pragma unroll
    for (int r = 1; r < 8; ++r) mx = fmaxf(mx, lg[r]);
    float e[8], se = 0.f;
#pragma unroll
    for (int r = 0; r < 8; ++r) { e[r] = expf(lg[r] - mx); se += e[r]; }

    // ---- top-2 (jax.lax.top_k: descending, lowest index wins ties) ----
    int r0 = 0; float v0 = lg[0];
#pragma unroll
    for (int r = 1; r < 8; ++r) if (lg[r] > v0) { v0 = lg[r]; r0 = r; }
    int r1 = (r0 == 0) ? 1 : 0; float v1 = lg[r1];
#pragma unroll
    for (int r = 0; r < 8; ++r) if (r != r1 && r != r0 && lg[r] > v1) { v1 = lg[r]; r1 = r; }
    float z = expf(v1 - v0);
    float gwt0 = 1.f / (1.f + z), gwt1 = z / (1.f + z);

    // ---- aux partial sums (1024 slots to spread atomic contention) ----
    {
        int slot = n & (AUX_SLOTS - 1);
        float* base = aux + slot * 16;
        float myp = 0.f, mym = 0.f;
#pragma unroll
        for (int r = 0; r < 8; ++r) {
            if (t == r) myp = e[r] / se;
            if (t - 8 == r) mym = (r == r0 || r == r1) ? 1.f : 0.f;
        }
        if (t < 8) atomicAdd(base + t, myp);
        else if (t < 16) atomicAdd(base + t, mym);
    }

    // ---- top-2 projections -> l2norm -> scores softmax -> mixture ----
    float pmix = 0.f;
#pragma unroll
    for (int k = 0; k < 2; ++k) {
        int r = k ? r1 : r0;
        float w = k ? gwt1 : gwt0;
        float u = Ub[r * 64 + t];
        const float* W = Uw + (size_t)(r * 768) * 64 + t;   // column t (h = lane)
#pragma unroll 8
        for (int d = 0; d < 768; ++d) u += xs[d] * W[(size_t)d * 64];
        float ss = u * u;
#pragma unroll
        for (int m = 1; m < 64; m <<= 1) ss += __shfl_xor(ss, m);
        us[t] = u * (1.f / fmaxf(sqrtf(ss), 1e-12f));
        __syncthreads();
        // scores: lane t = l
        float sc = 0.f;
        const float* v = vl + (size_t)(r * 64 + t) * 64;
#pragma unroll 8
        for (int h = 0; h < 64; ++h) sc += us[h] * v[h];
        float smx = sc;
#pragma unroll
        for (int m = 1; m < 64; m <<= 1) smx = fmaxf(smx, __shfl_xor(smx, m));
        float ex = expf(sc - smx);
        float ssum = ex;
#pragma unroll
        for (int m = 1; m < 64; m <<= 1) ssum += __shfl_xor(ssum, m);
        pmix += w * (ex / ssum);
        __syncthreads();   // us[] will be overwritten next k
    }
    ps[t] = pmix;
    __syncthreads();

    // ---- sequential cumsum (matches np.cumsum order) + selection on lane 0 ----
    if (t == 0) {
        float rn = rnd[n];
        float c = 0.f; int sel = 0; bool found = false;
        for (int l = 0; l < 64; ++l) {
            c += ps[l];
            if (!found && c > rn) { sel = l; found = true; }
        }
        out[n] = (float)sel;
        out[N + n] = logf(ps[sel]);
    }
}

__global__ void aux_kernel(const float* __restrict__ aux, float* __restrict__ out, int N) {
    int t = threadIdx.x;
    float acc = 0.f;
    if (t < 16) {
        for (int s = 0; s < AUX_SLOTS; ++s) acc += aux[s * 16 + t];
    }
    float other = __shfl(acc, (t + 8) & 63);
    float invN = 1.f / (float)N;
    float term = (t < 8) ? (acc * invN) * (other * invN) : 0.f;
#pragma unroll
    for (int m = 1; m < 64; m <<= 1) term += __shfl_xor(term, m);
    if (t == 0) out[2 * N] = 8.0f * 0.05f * term;
}

extern "C" void kernel_launch(void* const* d_in, const int* in_sizes, int n_in,
                              void* d_out, int out_size, void* d_ws, size_t ws_size,
                              hipStream_t stream) {
    const float* eh  = (const float*)d_in[0];
    const float* sr  = (const float*)d_in[1];
    const float* llm = (const float*)d_in[2];
    const float* rnd = (const float*)d_in[3];
    const float* gw  = (const float*)d_in[4];
    const float* gb  = (const float*)d_in[5];
    const float* Uw  = (const float*)d_in[6];
    const float* Ub  = (const float*)d_in[7];
    const float* Vw  = (const float*)d_in[8];
    const float* Vb  = (const float*)d_in[9];
    int N = in_sizes[0] / 384;

    float* vl  = (float*)d_ws;               // 8*64*64 floats = 128 KB
    float* aux = vl + 8 * 64 * 64;           // 1024*16 floats = 64 KB

    hipMemsetAsync(aux, 0, AUX_SLOTS * 16 * sizeof(float), stream);
    vl_kernel<<<8 * 64, 64, 0, stream>>>(llm, Vw, Vb, vl);
    main_kernel<<<N, 64, 0, stream>>>(eh, sr, rnd, gw, gb, Uw, Ub, vl, aux,
                                      (float*)d_out, N);
    aux_kernel<<<1, 64, 0, stream>>>(aux, (float*)d_out, N);
}

// Round 2
// 819.133 us; speedup vs baseline: 1.7881x; 1.7881x over previous
//
#include <hip/hip_runtime.h>
#include <math.h>

#define AUX_SLOTS 1024

// ---------------- vl: normalized V-projections, layout [R][H][L] ----------------
__global__ void vl_kernel(const float* __restrict__ llm, const float* __restrict__ Vw,
                          const float* __restrict__ Vb, float* __restrict__ vl) {
    int b = blockIdx.x;          // b = r*64 + l
    int r = b >> 6, l = b & 63;
    int t = threadIdx.x;         // h
    float acc = Vb[r * 64 + t];
    const float* w = Vw + (size_t)(r * 384) * 64 + t;
    const float* xr = llm + l * 384;
#pragma unroll 4
    for (int d = 0; d < 384; ++d) acc += xr[d] * w[(size_t)d * 64];
    float ss = acc * acc;
#pragma unroll
    for (int m = 1; m < 64; m <<= 1) ss += __shfl_xor(ss, m);
    float inv = 1.0f / fmaxf(sqrtf(ss), 1e-12f);
    vl[((size_t)r * 64 + t) * 64 + l] = acc * inv;   // [r][h][l]
}

// ---------------- gate: logits, top-2, aux partials, router counts ----------------
__global__ __launch_bounds__(256) void gate_kernel(
    const float* __restrict__ eh, const float* __restrict__ sr,
    const float* __restrict__ gw, const float* __restrict__ gb,
    int* __restrict__ rinfo, float* __restrict__ wbuf,
    float* __restrict__ aux, int* __restrict__ cnt, int N)
{
    __shared__ int lcnt[8];
    int tid = threadIdx.x;
    if (tid < 8) lcnt[tid] = 0;
    __syncthreads();
    int wave = tid >> 6, lane = tid & 63;
    int wgid = blockIdx.x * 4 + wave;
    float gbr[8];
#pragma unroll
    for (int r = 0; r < 8; ++r) gbr[r] = gb[r];
    float aux_acc = 0.f;

    for (int rr = 0; rr < 8; ++rr) {
        int row = wgid * 8 + rr;
        const float4* pa = (const float4*)(eh + (size_t)row * 384);
        const float4* pb = (const float4*)(sr + (size_t)row * 384);
        float4 xv0 = pa[lane];                                      // f = lane
        const float4* p1 = (lane < 32) ? (pa + 64 + lane) : (pb + (lane - 32));
        float4 xv1 = *p1;                                           // f = lane+64
        float4 xv2 = pb[lane + 32];                                 // f = lane+128

        float lg[8];
#pragma unroll
        for (int r = 0; r < 8; ++r) lg[r] = 0.f;
        {
            const float* g0 = gw + (size_t)lane * 32;
            const float* g1 = gw + (size_t)(lane + 64) * 32;
            const float* g2 = gw + (size_t)(lane + 128) * 32;
            float xd;
#pragma unroll
            for (int dd = 0; dd < 4; ++dd) {
                xd = (dd == 0) ? xv0.x : (dd == 1) ? xv0.y : (dd == 2) ? xv0.z : xv0.w;
#pragma unroll
                for (int r = 0; r < 8; ++r) lg[r] += xd * g0[dd * 8 + r];
            }
#pragma unroll
            for (int dd = 0; dd < 4; ++dd) {
                xd = (dd == 0) ? xv1.x : (dd == 1) ? xv1.y : (dd == 2) ? xv1.z : xv1.w;
#pragma unroll
                for (int r = 0; r < 8; ++r) lg[r] += xd * g1[dd * 8 + r];
            }
#pragma unroll
            for (int dd = 0; dd < 4; ++dd) {
                xd = (dd == 0) ? xv2.x : (dd == 1) ? xv2.y : (dd == 2) ? xv2.z : xv2.w;
#pragma unroll
                for (int r = 0; r < 8; ++r) lg[r] += xd * g2[dd * 8 + r];
            }
        }
#pragma unroll
        for (int m = 1; m < 64; m <<= 1) {
#pragma unroll
            for (int r = 0; r < 8; ++r) lg[r] += __shfl_xor(lg[r], m);
        }
#pragma unroll
        for (int r = 0; r < 8; ++r) lg[r] += gbr[r];

        float mx = lg[0];
#pragma unroll
        for (int r = 1; r < 8; ++r) mx = fmaxf(mx, lg[r]);
        float e8[8], se = 0.f;
#pragma unroll
        for (int r = 0; r < 8; ++r) { e8[r] = expf(lg[r] - mx); se += e8[r]; }

        int r0 = 0; float v0 = lg[0];
#pragma unroll
        for (int r = 1; r < 8; ++r) if (lg[r] > v0) { v0 = lg[r]; r0 = r; }
        int r1 = (r0 == 0) ? 1 : 0; float v1 = lg[r1];
#pragma unroll
        for (int r = 0; r < 8; ++r) if (r != r1 && r != r0 && lg[r] > v1) { v1 = lg[r]; r1 = r; }
        float z = expf(v1 - v0);
        float w0 = 1.f / (1.f + z), w1 = z / (1.f + z);

        if (lane == 0) {
            rinfo[row] = r0 | (r1 << 4);
            wbuf[2 * row] = w0; wbuf[2 * row + 1] = w1;
            atomicAdd(&lcnt[r0], 1);
            atomicAdd(&lcnt[r1], 1);
        }
#pragma unroll
        for (int r2 = 0; r2 < 8; ++r2) {
            if (lane == r2) aux_acc += e8[r2] / se;
            if (lane - 8 == r2) aux_acc += (r2 == r0 || r2 == r1) ? 1.f : 0.f;
        }
    }
    if (lane < 16) atomicAdd(aux + ((size_t)(wgid & (AUX_SLOTS - 1)) * 16) + lane, aux_acc);
    __syncthreads();
    if (tid < 8) atomicAdd(&cnt[tid], lcnt[tid]);
}

__global__ void prefix_kernel(const int* __restrict__ cnt, int* __restrict__ cur,
                              int* __restrict__ off) {
    if (threadIdx.x == 0) {
        int s = 0;
        for (int r = 0; r < 8; ++r) { off[r] = s; cur[r] = s; s += cnt[r]; }
    }
}

__global__ __launch_bounds__(256) void scatter_kernel(
    const int* __restrict__ rinfo, const float* __restrict__ wbuf,
    int* __restrict__ cur, int* __restrict__ ent, float* __restrict__ ewt, int N)
{
    __shared__ int hist[8], lbase[8], lcur[8];
    int tid = threadIdx.x;
    if (tid < 8) { hist[tid] = 0; lcur[tid] = 0; }
    __syncthreads();
    int rows = N >> 6;                 // 1024 rows per block, 64 blocks
    int base = blockIdx.x * rows;
    for (int i = tid; i < rows; i += 256) {
        int ri = rinfo[base + i];
        atomicAdd(&hist[ri & 15], 1);
        atomicAdd(&hist[(ri >> 4) & 15], 1);
    }
    __syncthreads();
    if (tid < 8) lbase[tid] = atomicAdd(&cur[tid], hist[tid]);
    __syncthreads();
    for (int i = tid; i < rows; i += 256) {
        int row = base + i;
        int ri = rinfo[row];
        int r0 = ri & 15, r1 = (ri >> 4) & 15;
        int p0 = lbase[r0] + atomicAdd(&lcur[r0], 1);
        ent[p0] = row << 1;       ewt[p0] = wbuf[2 * row];
        int p1 = lbase[r1] + atomicAdd(&lcur[r1], 1);
        ent[p1] = (row << 1) | 1; ewt[p1] = wbuf[2 * row + 1];
    }
}

// ---------------- fused projection GEMM + l2norm + scores + softmax ----------------
__global__ __launch_bounds__(128, 2) void gemm_kernel(
    const float* __restrict__ eh, const float* __restrict__ sr,
    const float* __restrict__ Uw, const float* __restrict__ Ub,
    const float* __restrict__ vl, const int* __restrict__ ent,
    const float* __restrict__ ewt, const int* __restrict__ off,
    const int* __restrict__ cnt, float* __restrict__ probs)
{
    int r = blockIdx.y;
    int count = cnt[r];
    int tile = blockIdx.x;
    if (tile * 128 >= count) return;
    int base = off[r] + tile * 128;

    __shared__ float xs[128 * 64];   // x tile, float4-swizzled: slot = row*16 + (k4 ^ (row>>3 & 7))
    __shared__ float us[64 * 64];    // U chunk [k][h]; later reused for vl [h][l4 ^ (h>>3)]
    __shared__ int   sent[128];
    __shared__ float swt[128];

    int tid = threadIdx.x;
    int tx = tid & 7, ty = tid >> 3;   // 16 ty x 8 tx; micro-tile: rows 8ty.., h 8tx..
    float4* xs4 = (float4*)xs;
    float4* us4 = (float4*)us;

    {
        bool act = (tile * 128 + tid) < count;
        sent[tid] = act ? ent[base + tid] : -1;
        swt[tid]  = act ? ewt[base + tid] : 0.f;
    }

    float acc[8][8];
#pragma unroll
    for (int i = 0; i < 8; ++i)
#pragma unroll
        for (int j = 0; j < 8; ++j) acc[i][j] = 0.f;

    for (int c = 0; c < 12; ++c) {
        __syncthreads();
        {   // stage A (x rows), coalesced global, swizzled LDS
            int k4 = tid & 15, g = tid >> 4;
            const float* xsrc = (c < 6) ? eh : sr;
            int dd0 = ((c < 6) ? c : c - 6) * 64;
#pragma unroll
            for (int p = 0; p < 16; ++p) {
                int rloc = g + p * 8;
                int e = sent[rloc];
                int row = (e < 0) ? 0 : (e >> 1);
                float4 v = ((const float4*)(xsrc + (size_t)row * 384 + dd0))[k4];
                xs4[rloc * 16 + (k4 ^ ((rloc >> 3) & 7))] = v;
            }
        }
        {   // stage B (U chunk), linear copy
            const float4* pu = (const float4*)(Uw + ((size_t)r * 768 + (size_t)c * 64) * 64);
#pragma unroll
            for (int p = 0; p < 8; ++p) us4[tid + p * 128] = pu[tid + p * 128];
        }
        __syncthreads();
        for (int k4 = 0; k4 < 16; ++k4) {
            float4 a[8];
#pragma unroll
            for (int i = 0; i < 8; ++i)
                a[i] = xs4[(8 * ty + i) * 16 + (k4 ^ (ty & 7))];
#pragma unroll
            for (int j = 0; j < 4; ++j) {
                int kk = k4 * 4 + j;
                float4 b0 = us4[kk * 16 + tx * 2];
                float4 b1 = us4[kk * 16 + tx * 2 + 1];
#pragma unroll
                for (int i = 0; i < 8; ++i) {
                    float av = (j == 0) ? a[i].x : (j == 1) ? a[i].y : (j == 2) ? a[i].z : a[i].w;
                    acc[i][0] += av * b0.x; acc[i][1] += av * b0.y;
                    acc[i][2] += av * b0.z; acc[i][3] += av * b0.w;
                    acc[i][4] += av * b1.x; acc[i][5] += av * b1.y;
                    acc[i][6] += av * b1.z; acc[i][7] += av * b1.w;
                }
            }
        }
    }

    // bias + l2-normalize rows (ss spread over tx; xor-shfl over masks 1,2,4)
    float ub[8];
#pragma unroll
    for (int j = 0; j < 8; ++j) ub[j] = Ub[r * 64 + 8 * tx + j];
#pragma unroll
    for (int i = 0; i < 8; ++i) {
        float ss = 0.f;
#pragma unroll
        for (int j = 0; j < 8; ++j) { acc[i][j] += ub[j]; ss += acc[i][j] * acc[i][j]; }
#pragma unroll
        for (int m = 1; m <= 4; m <<= 1) ss += __shfl_xor(ss, m);
        float inv = 1.0f / fmaxf(sqrtf(ss), 1e-12f);
#pragma unroll
        for (int j = 0; j < 8; ++j) acc[i][j] *= inv;
    }

    // stage vl[r] into us (swizzled)
    __syncthreads();
    {
        const float4* pv = (const float4*)(vl + (size_t)r * 4096);
#pragma unroll
        for (int p = 0; p < 8; ++p) {
            int idx = tid + p * 128;
            int h = idx >> 4, l4 = idx & 15;
            us4[h * 16 + (l4 ^ ((h >> 3) & 7))] = pv[idx];
        }
    }
    __syncthreads();

    // scores = u . vl  (partial over own 8 h, xor-tree over tx, keep when tx==lc)
    float sc[8][8];
    for (int lc = 0; lc < 8; ++lc) {
        float part[8][8];
#pragma unroll
        for (int i = 0; i < 8; ++i)
#pragma unroll
            for (int j = 0; j < 8; ++j) part[i][j] = 0.f;
#pragma unroll
        for (int j = 0; j < 8; ++j) {
            int h = 8 * tx + j;
            float4 v0 = us4[h * 16 + ((2 * lc) ^ tx)];
            float4 v1 = us4[h * 16 + ((2 * lc + 1) ^ tx)];
#pragma unroll
            for (int i = 0; i < 8; ++i) {
                float uv = acc[i][j];
                part[i][0] += uv * v0.x; part[i][1] += uv * v0.y;
                part[i][2] += uv * v0.z; part[i][3] += uv * v0.w;
                part[i][4] += uv * v1.x; part[i][5] += uv * v1.y;
                part[i][6] += uv * v1.z; part[i][7] += uv * v1.w;
            }
        }
#pragma unroll
        for (int m = 1; m <= 4; m <<= 1)
#pragma unroll
            for (int i = 0; i < 8; ++i)
#pragma unroll
                for (int j = 0; j < 8; ++j) part[i][j] += __shfl_xor(part[i][j], m);
        if (tx == lc) {
#pragma unroll
            for (int i = 0; i < 8; ++i)
#pragma unroll
                for (int j = 0; j < 8; ++j) sc[i][j] = part[i][j];
        }
    }

    // softmax over l (row stats via xor-shfl over tx) + gate-weight scale + store
#pragma unroll
    for (int i = 0; i < 8; ++i) {
        float mx = sc[i][0];
#pragma unroll
        for (int j = 1; j < 8; ++j) mx = fmaxf(mx, sc[i][j]);
#pragma unroll
        for (int m = 1; m <= 4; m <<= 1) mx = fmaxf(mx, __shfl_xor(mx, m));
        float e[8], ssum = 0.f;
#pragma unroll
        for (int j = 0; j < 8; ++j) { e[j] = expf(sc[i][j] - mx); ssum += e[j]; }
#pragma unroll
        for (int m = 1; m <= 4; m <<= 1) ssum += __shfl_xor(ssum, m);
        int ei = sent[8 * ty + i];
        if (ei >= 0) {
            float w = swt[8 * ty + i];
            float4 o0, o1;
            o0.x = (e[0] / ssum) * w; o0.y = (e[1] / ssum) * w;
            o0.z = (e[2] / ssum) * w; o0.w = (e[3] / ssum) * w;
            o1.x = (e[4] / ssum) * w; o1.y = (e[5] / ssum) * w;
            o1.z = (e[6] / ssum) * w; o1.w = (e[7] / ssum) * w;
            size_t bo = (size_t)(ei >> 1) * 128 + (size_t)(ei & 1) * 64 + 8 * tx;
            *(float4*)(probs + bo) = o0;
            *(float4*)(probs + bo + 4) = o1;
        }
    }
}

// ---------------- combine: p = k0+k1, sequential cumsum, select, log ----------------
__global__ __launch_bounds__(256) void combine_kernel(
    const float* __restrict__ probs, const float* __restrict__ rnd,
    float* __restrict__ out, int N)
{
    int w = threadIdx.x >> 6, lane = threadIdx.x & 63;
    int n = blockIdx.x * 4 + w;
    float p = probs[(size_t)n * 128 + lane] + probs[(size_t)n * 128 + 64 + lane];
    float rn = rnd[n];
    float c = 0.f; int sel = 0; bool found = false;
    for (int l = 0; l < 64; ++l) {
        float v = __shfl(p, l);
        c += v;
        if (!found && c > rn) { sel = l; found = true; }
    }
    if (lane == 0) {
        out[n] = (float)sel;
    }
    float pv = __shfl(p, sel);
    if (lane == 0) out[N + n] = logf(pv);
}

__global__ void aux_kernel(const float* __restrict__ aux, float* __restrict__ out, int N) {
    int t = threadIdx.x;
    float acc = 0.f;
    if (t < 16) {
        for (int s = 0; s < AUX_SLOTS; ++s) acc += aux[s * 16 + t];
    }
    float other = __shfl(acc, (t + 8) & 63);
    float invN = 1.f / (float)N;
    float term = (t < 8) ? (acc * invN) * (other * invN) : 0.f;
#pragma unroll
    for (int m = 1; m < 64; m <<= 1) term += __shfl_xor(term, m);
    if (t == 0) out[2 * N] = 8.0f * 0.05f * term;
}

extern "C" void kernel_launch(void* const* d_in, const int* in_sizes, int n_in,
                              void* d_out, int out_size, void* d_ws, size_t ws_size,
                              hipStream_t stream) {
    const float* eh  = (const float*)d_in[0];
    const float* sr  = (const float*)d_in[1];
    const float* llm = (const float*)d_in[2];
    const float* rnd = (const float*)d_in[3];
    const float* gw  = (const float*)d_in[4];
    const float* gb  = (const float*)d_in[5];
    const float* Uw  = (const float*)d_in[6];
    const float* Ub  = (const float*)d_in[7];
    const float* Vw  = (const float*)d_in[8];
    const float* Vb  = (const float*)d_in[9];
    int N = in_sizes[0] / 384;

    float* vl    = (float*)d_ws;              // 32768
    float* aux   = vl + 32768;                // 16384
    int*   cnt   = (int*)(aux + 16384);       // 8
    int*   cur   = cnt + 8;                   // 8
    int*   off   = cur + 8;                   // 8
    int*   rinfo = off + 8;                   // N
    float* wbuf  = (float*)(rinfo + N);       // 2N
    int*   ent   = (int*)(wbuf + 2 * N);      // 2N
    float* ewt   = (float*)(ent + 2 * N);     // 2N
    float* probs = ewt + 2 * N;               // N*128

    hipMemsetAsync(aux, 0, (16384 + 16) * sizeof(float), stream);
    vl_kernel<<<512, 64, 0, stream>>>(llm, Vw, Vb, vl);
    gate_kernel<<<N / 32, 256, 0, stream>>>(eh, sr, gw, gb, rinfo, wbuf, aux, cnt, N);
    prefix_kernel<<<1, 64, 0, stream>>>(cnt, cur, off);
    scatter_kernel<<<64, 256, 0, stream>>>(rinfo, wbuf, cur, ent, ewt, N);
    gemm_kernel<<<dim3((N + 127) / 128, 8), 128, 0, stream>>>(eh, sr, Uw, Ub, vl, ent, ewt,
                                                              off, cnt, probs);
    combine_kernel<<<N / 4, 256, 0, stream>>>(probs, rnd, (float*)d_out, N);
    aux_kernel<<<1, 64, 0, stream>>>(aux, (float*)d_out, N);
}

// Round 3
// 732.880 us; speedup vs baseline: 1.9986x; 1.1177x over previous
//
#include <hip/hip_runtime.h>
#include <math.h>

#define AUX_SLOTS 1024

// ---------------- vl: normalized V-projections, layout [R][H][L] ----------------
__global__ void vl_kernel(const float* __restrict__ llm, const float* __restrict__ Vw,
                          const float* __restrict__ Vb, float* __restrict__ vl) {
    int b = blockIdx.x;          // b = r*64 + l
    int r = b >> 6, l = b & 63;
    int t = threadIdx.x;         // h
    float acc = Vb[r * 64 + t];
    const float* w = Vw + (size_t)(r * 384) * 64 + t;
    const float* xr = llm + l * 384;
#pragma unroll 4
    for (int d = 0; d < 384; ++d) acc += xr[d] * w[(size_t)d * 64];
    float ss = acc * acc;
#pragma unroll
    for (int m = 1; m < 64; m <<= 1) ss += __shfl_xor(ss, m);
    float inv = 1.0f / fmaxf(sqrtf(ss), 1e-12f);
    vl[((size_t)r * 64 + t) * 64 + l] = acc * inv;   // [r][h][l]
}

// ---------------- gate: logits, top-2, aux partials, router counts ----------------
__global__ __launch_bounds__(256) void gate_kernel(
    const float* __restrict__ eh, const float* __restrict__ sr,
    const float* __restrict__ gw, const float* __restrict__ gb,
    int* __restrict__ rinfo, float* __restrict__ wbuf,
    float* __restrict__ aux, int* __restrict__ cnt, int N)
{
    __shared__ int lcnt[8];
    int tid = threadIdx.x;
    if (tid < 8) lcnt[tid] = 0;
    __syncthreads();
    int wave = tid >> 6, lane = tid & 63;
    int wgid = blockIdx.x * 4 + wave;
    float gbr[8];
#pragma unroll
    for (int r = 0; r < 8; ++r) gbr[r] = gb[r];
    float aux_acc = 0.f;

    for (int rr = 0; rr < 8; ++rr) {
        int row = wgid * 8 + rr;
        const float4* pa = (const float4*)(eh + (size_t)row * 384);
        const float4* pb = (const float4*)(sr + (size_t)row * 384);
        float4 xv0 = pa[lane];
        const float4* p1 = (lane < 32) ? (pa + 64 + lane) : (pb + (lane - 32));
        float4 xv1 = *p1;
        float4 xv2 = pb[lane + 32];

        float lg[8];
#pragma unroll
        for (int r = 0; r < 8; ++r) lg[r] = 0.f;
        {
            const float* g0 = gw + (size_t)lane * 32;
            const float* g1 = gw + (size_t)(lane + 64) * 32;
            const float* g2 = gw + (size_t)(lane + 128) * 32;
            float xd;
#pragma unroll
            for (int dd = 0; dd < 4; ++dd) {
                xd = (dd == 0) ? xv0.x : (dd == 1) ? xv0.y : (dd == 2) ? xv0.z : xv0.w;
#pragma unroll
                for (int r = 0; r < 8; ++r) lg[r] += xd * g0[dd * 8 + r];
            }
#pragma unroll
            for (int dd = 0; dd < 4; ++dd) {
                xd = (dd == 0) ? xv1.x : (dd == 1) ? xv1.y : (dd == 2) ? xv1.z : xv1.w;
#pragma unroll
                for (int r = 0; r < 8; ++r) lg[r] += xd * g1[dd * 8 + r];
            }
#pragma unroll
            for (int dd = 0; dd < 4; ++dd) {
                xd = (dd == 0) ? xv2.x : (dd == 1) ? xv2.y : (dd == 2) ? xv2.z : xv2.w;
#pragma unroll
                for (int r = 0; r < 8; ++r) lg[r] += xd * g2[dd * 8 + r];
            }
        }
#pragma unroll
        for (int m = 1; m < 64; m <<= 1) {
#pragma unroll
            for (int r = 0; r < 8; ++r) lg[r] += __shfl_xor(lg[r], m);
        }
#pragma unroll
        for (int r = 0; r < 8; ++r) lg[r] += gbr[r];

        float mx = lg[0];
#pragma unroll
        for (int r = 1; r < 8; ++r) mx = fmaxf(mx, lg[r]);
        float e8[8], se = 0.f;
#pragma unroll
        for (int r = 0; r < 8; ++r) { e8[r] = expf(lg[r] - mx); se += e8[r]; }

        int r0 = 0; float v0 = lg[0];
#pragma unroll
        for (int r = 1; r < 8; ++r) if (lg[r] > v0) { v0 = lg[r]; r0 = r; }
        int r1 = (r0 == 0) ? 1 : 0; float v1 = lg[r1];
#pragma unroll
        for (int r = 0; r < 8; ++r) if (r != r1 && r != r0 && lg[r] > v1) { v1 = lg[r]; r1 = r; }
        float z = expf(v1 - v0);
        float w0 = 1.f / (1.f + z), w1 = z / (1.f + z);

        if (lane == 0) {
            rinfo[row] = r0 | (r1 << 4);
            wbuf[2 * row] = w0; wbuf[2 * row + 1] = w1;
            atomicAdd(&lcnt[r0], 1);
            atomicAdd(&lcnt[r1], 1);
        }
#pragma unroll
        for (int r2 = 0; r2 < 8; ++r2) {
            if (lane == r2) aux_acc += e8[r2] / se;
            if (lane - 8 == r2) aux_acc += (r2 == r0 || r2 == r1) ? 1.f : 0.f;
        }
    }
    if (lane < 16) atomicAdd(aux + ((size_t)(wgid & (AUX_SLOTS - 1)) * 16) + lane, aux_acc);
    __syncthreads();
    if (tid < 8) atomicAdd(&cnt[tid], lcnt[tid]);
}

__global__ void prefix_kernel(const int* __restrict__ cnt, int* __restrict__ cur,
                              int* __restrict__ off) {
    if (threadIdx.x == 0) {
        int s = 0;
        for (int r = 0; r < 8; ++r) { off[r] = s; cur[r] = s; s += cnt[r]; }
    }
}

__global__ __launch_bounds__(256) void scatter_kernel(
    const int* __restrict__ rinfo, const float* __restrict__ wbuf,
    int* __restrict__ cur, int* __restrict__ ent, float* __restrict__ ewt, int N)
{
    __shared__ int hist[8], lbase[8], lcur[8];
    int tid = threadIdx.x;
    if (tid < 8) { hist[tid] = 0; lcur[tid] = 0; }
    __syncthreads();
    int rows = N >> 8;                 // 256 rows per block, 256 blocks
    int base = blockIdx.x * rows;
    for (int i = tid; i < rows; i += 256) {
        int ri = rinfo[base + i];
        atomicAdd(&hist[ri & 15], 1);
        atomicAdd(&hist[(ri >> 4) & 15], 1);
    }
    __syncthreads();
    if (tid < 8) lbase[tid] = atomicAdd(&cur[tid], hist[tid]);
    __syncthreads();
    for (int i = tid; i < rows; i += 256) {
        int row = base + i;
        int ri = rinfo[row];
        int r0 = ri & 15, r1 = (ri >> 4) & 15;
        int p0 = lbase[r0] + atomicAdd(&lcur[r0], 1);
        ent[p0] = row << 1;       ewt[p0] = wbuf[2 * row];
        int p1 = lbase[r1] + atomicAdd(&lcur[r1], 1);
        ent[p1] = (row << 1) | 1; ewt[p1] = wbuf[2 * row + 1];
    }
}

// ---------------- fused projection GEMM + l2norm + scores + softmax ----------------
// tile: 256 rows x 64 h, 256 threads, 8x8 micro-tile, K-chunk 32
__global__ __launch_bounds__(256, 3) void gemm_kernel(
    const float* __restrict__ eh, const float* __restrict__ sr,
    const float* __restrict__ Uw, const float* __restrict__ Ub,
    const float* __restrict__ vl, const int* __restrict__ ent,
    const float* __restrict__ ewt, const int* __restrict__ off,
    const int* __restrict__ cnt, float* __restrict__ probs)
{
    int r = blockIdx.y;
    int count = cnt[r];
    int tile = blockIdx.x;
    if (tile * 256 >= count) return;
    int base = off[r] + tile * 256;

    __shared__ float xs[256 * 32];   // 32 KB, f4-swizzled [row][k4 ^ ((row>>3)&7)]
    __shared__ float us[32 * 64];    // 8 KB, U chunk [k][h]
    __shared__ int   sent[256];
    __shared__ float swt[256];

    int tid = threadIdx.x;
    int tx = tid & 7, ty = tid >> 3;   // ty 0..31, rows 8ty..8ty+7; h 8tx..8tx+7
    float4* xs4 = (float4*)xs;
    float4* us4 = (float4*)us;

    {
        bool act = (tile * 256 + tid) < count;
        sent[tid] = act ? ent[base + tid] : -1;
        swt[tid]  = act ? ewt[base + tid] : 0.f;
    }
    __syncthreads();

    // cache this thread's staging row ids (rloc = ty + 32p)
    int rowp[8];
#pragma unroll
    for (int p = 0; p < 8; ++p) {
        int e = sent[ty + 32 * p];
        rowp[p] = (e < 0) ? 0 : (e >> 1);
    }

    float acc[8][8];
#pragma unroll
    for (int i = 0; i < 8; ++i)
#pragma unroll
        for (int j = 0; j < 8; ++j) acc[i][j] = 0.f;

    for (int c = 0; c < 24; ++c) {
        const float* xsrc = (c < 12) ? eh : sr;
        int dd0 = ((c < 12) ? c : c - 12) * 32;
        {   // stage x: 8 f4 per thread, 128B contiguous per row
#pragma unroll
            for (int p = 0; p < 8; ++p) {
                int rloc = ty + 32 * p;
                float4 v = ((const float4*)(xsrc + (size_t)rowp[p] * 384 + dd0))[tx];
                xs4[rloc * 8 + (tx ^ ((rloc >> 3) & 7))] = v;
            }
        }
        {   // stage U chunk [32k][64h], linear
            const float4* pu = (const float4*)(Uw + ((size_t)r * 768 + (size_t)c * 32) * 64);
            us4[tid] = pu[tid];
            us4[tid + 256] = pu[tid + 256];
        }
        __syncthreads();
#pragma unroll
        for (int k4 = 0; k4 < 8; ++k4) {
            float4 a[8];
#pragma unroll
            for (int i = 0; i < 8; ++i)
                a[i] = xs4[(8 * ty + i) * 8 + (k4 ^ (ty & 7))];
#pragma unroll
            for (int j = 0; j < 4; ++j) {
                float4 b0 = us4[(k4 * 4 + j) * 16 + tx * 2];
                float4 b1 = us4[(k4 * 4 + j) * 16 + tx * 2 + 1];
#pragma unroll
                for (int i = 0; i < 8; ++i) {
                    float av = (j == 0) ? a[i].x : (j == 1) ? a[i].y : (j == 2) ? a[i].z : a[i].w;
                    acc[i][0] += av * b0.x; acc[i][1] += av * b0.y;
                    acc[i][2] += av * b0.z; acc[i][3] += av * b0.w;
                    acc[i][4] += av * b1.x; acc[i][5] += av * b1.y;
                    acc[i][6] += av * b1.z; acc[i][7] += av * b1.w;
                }
            }
        }
        __syncthreads();
    }

    // bias + l2-normalize rows (partial over tx, xor-shfl 1,2,4)
    float ub[8];
#pragma unroll
    for (int j = 0; j < 8; ++j) ub[j] = Ub[r * 64 + 8 * tx + j];
#pragma unroll
    for (int i = 0; i < 8; ++i) {
        float ss = 0.f;
#pragma unroll
        for (int j = 0; j < 8; ++j) { acc[i][j] += ub[j]; ss += acc[i][j] * acc[i][j]; }
#pragma unroll
        for (int m = 1; m <= 4; m <<= 1) ss += __shfl_xor(ss, m);
        float inv = 1.0f / fmaxf(sqrtf(ss), 1e-12f);
#pragma unroll
        for (int j = 0; j < 8; ++j) acc[i][j] *= inv;
    }

    // stage vl[r] (16 KB) into xs, swizzled [h][l4 ^ ((h>>3)&7)]
    {
        const float4* pv = (const float4*)(vl + (size_t)r * 4096);
#pragma unroll
        for (int p = 0; p < 4; ++p) {
            int idx = tid + p * 256;
            int h = idx >> 4, l4 = idx & 15;
            xs4[h * 16 + (l4 ^ ((h >> 3) & 7))] = pv[idx];
        }
    }
    __syncthreads();

    // scores + softmax + store, in two 4-row halves (register pressure)
#pragma unroll
    for (int ih = 0; ih < 8; ih += 4) {
        float sc[4][8];
        for (int lc = 0; lc < 8; ++lc) {
            float part[4][8];
#pragma unroll
            for (int i = 0; i < 4; ++i)
#pragma unroll
                for (int j = 0; j < 8; ++j) part[i][j] = 0.f;
#pragma unroll
            for (int j = 0; j < 8; ++j) {
                int h = 8 * tx + j;
                float4 v0 = xs4[h * 16 + ((2 * lc) ^ tx)];
                float4 v1 = xs4[h * 16 + ((2 * lc + 1) ^ tx)];
#pragma unroll
                for (int i = 0; i < 4; ++i) {
                    float uv = acc[ih + i][j];
                    part[i][0] += uv * v0.x; part[i][1] += uv * v0.y;
                    part[i][2] += uv * v0.z; part[i][3] += uv * v0.w;
                    part[i][4] += uv * v1.x; part[i][5] += uv * v1.y;
                    part[i][6] += uv * v1.z; part[i][7] += uv * v1.w;
                }
            }
#pragma unroll
            for (int m = 1; m <= 4; m <<= 1)
#pragma unroll
                for (int i = 0; i < 4; ++i)
#pragma unroll
                    for (int j = 0; j < 8; ++j) part[i][j] += __shfl_xor(part[i][j], m);
            if (tx == lc) {
#pragma unroll
                for (int i = 0; i < 4; ++i)
#pragma unroll
                    for (int j = 0; j < 8; ++j) sc[i][j] = part[i][j];
            }
        }
#pragma unroll
        for (int i = 0; i < 4; ++i) {
            float mx = sc[i][0];
#pragma unroll
            for (int j = 1; j < 8; ++j) mx = fmaxf(mx, sc[i][j]);
#pragma unroll
            for (int m = 1; m <= 4; m <<= 1) mx = fmaxf(mx, __shfl_xor(mx, m));
            float e[8], ssum = 0.f;
#pragma unroll
            for (int j = 0; j < 8; ++j) { e[j] = expf(sc[i][j] - mx); ssum += e[j]; }
#pragma unroll
            for (int m = 1; m <= 4; m <<= 1) ssum += __shfl_xor(ssum, m);
            int rloc = 8 * ty + ih + i;
            int ei = sent[rloc];
            if (ei >= 0) {
                float w = swt[rloc];
                float4 o0, o1;
                o0.x = (e[0] / ssum) * w; o0.y = (e[1] / ssum) * w;
                o0.z = (e[2] / ssum) * w; o0.w = (e[3] / ssum) * w;
                o1.x = (e[4] / ssum) * w; o1.y = (e[5] / ssum) * w;
                o1.z = (e[6] / ssum) * w; o1.w = (e[7] / ssum) * w;
                size_t bo = (size_t)(ei >> 1) * 128 + (size_t)(ei & 1) * 64 + 8 * tx;
                *(float4*)(probs + bo) = o0;
                *(float4*)(probs + bo + 4) = o1;
            }
        }
    }
}

// ---------------- combine: p = k0+k1, sequential cumsum, select, log ----------------
__global__ __launch_bounds__(256) void combine_kernel(
    const float* __restrict__ probs, const float* __restrict__ rnd,
    float* __restrict__ out, int N)
{
    int w = threadIdx.x >> 6, lane = threadIdx.x & 63;
    int n = blockIdx.x * 4 + w;
    float p = probs[(size_t)n * 128 + lane] + probs[(size_t)n * 128 + 64 + lane];
    float rn = rnd[n];
    float c = 0.f; int sel = 0; bool found = false;
    for (int l = 0; l < 64; ++l) {
        float v = __shfl(p, l);
        c += v;
        if (!found && c > rn) { sel = l; found = true; }
    }
    float pv = __shfl(p, sel);
    if (lane == 0) {
        out[n] = (float)sel;
        out[N + n] = logf(pv);
    }
}

__global__ __launch_bounds__(256) void aux_kernel(const float* __restrict__ aux,
                                                  float* __restrict__ out, int N) {
    __shared__ float red[256];
    int tid = threadIdx.x;
    int j = tid & 15, s0 = tid >> 4;
    float acc = 0.f;
    for (int s = s0; s < AUX_SLOTS; s += 16) acc += aux[s * 16 + j];
    red[tid] = acc;
    __syncthreads();
    if (tid < 16) {
        float a = 0.f;
        for (int g = 0; g < 16; ++g) a += red[g * 16 + tid];
        red[tid] = a;
    }
    __syncthreads();
    if (tid == 0) {
        float invN = 1.f / (float)N;
        float t = 0.f;
        for (int r2 = 0; r2 < 8; ++r2) t += (red[r2] * invN) * (red[8 + r2] * invN);
        out[2 * N] = 8.0f * 0.05f * t;
    }
}

extern "C" void kernel_launch(void* const* d_in, const int* in_sizes, int n_in,
                              void* d_out, int out_size, void* d_ws, size_t ws_size,
                              hipStream_t stream) {
    const float* eh  = (const float*)d_in[0];
    const float* sr  = (const float*)d_in[1];
    const float* llm = (const float*)d_in[2];
    const float* rnd = (const float*)d_in[3];
    const float* gw  = (const float*)d_in[4];
    const float* gb  = (const float*)d_in[5];
    const float* Uw  = (const float*)d_in[6];
    const float* Ub  = (const float*)d_in[7];
    const float* Vw  = (const float*)d_in[8];
    const float* Vb  = (const float*)d_in[9];
    int N = in_sizes[0] / 384;

    float* vl    = (float*)d_ws;              // 32768
    float* aux   = vl + 32768;                // 16384
    int*   cnt   = (int*)(aux + 16384);       // 8
    int*   cur   = cnt + 8;                   // 8
    int*   off   = cur + 8;                   // 8
    int*   rinfo = off + 8;                   // N
    float* wbuf  = (float*)(rinfo + N);       // 2N
    int*   ent   = (int*)(wbuf + 2 * N);      // 2N
    float* ewt   = (float*)(ent + 2 * N);     // 2N
    float* probs = ewt + 2 * N;               // N*128

    hipMemsetAsync(aux, 0, (16384 + 16) * sizeof(float), stream);
    vl_kernel<<<512, 64, 0, stream>>>(llm, Vw, Vb, vl);
    gate_kernel<<<N / 32, 256, 0, stream>>>(eh, sr, gw, gb, rinfo, wbuf, aux, cnt, N);
    prefix_kernel<<<1, 64, 0, stream>>>(cnt, cur, off);
    scatter_kernel<<<256, 256, 0, stream>>>(rinfo, wbuf, cur, ent, ewt, N);
    gemm_kernel<<<dim3(512, 8), 256, 0, stream>>>(eh, sr, Uw, Ub, vl, ent, ewt,
                                                  off, cnt, probs);
    combine_kernel<<<N / 4, 256, 0, stream>>>(probs, rnd, (float*)d_out, N);
    aux_kernel<<<1, 256, 0, stream>>>(aux, (float*)d_out, N);
}